// Round 6
// baseline (341.430 us; speedup 1.0000x reference)
//
#include <hip/hip_runtime.h>
#include <stdint.h>

typedef unsigned long long ull;

#define Bc 8
#define Cc 64
#define Hc 256
#define Wc 256
#define Vc (Hc*Wc)            // 65536
#define REc ((Hc-1)*Wc)       // 65280 row (down) edges
#define Ec (REc + Hc*(Wc-1))  // 130560 total edges
#define VM1 (Vc-1)            // 65535
#define INF64 0xFFFFFFFFFFFFFFFFull
#define NRA 18                // act slots (rounds 0..17)
#define NKR 16                // round kernels r=1..16 (components halve per hook)
#define EPB 2048              // edges per block in compaction
#define BPB 64                // blocks per batch = ceil(Ec/EPB)

__device__ __forceinline__ void edge_uv(int e, int& u, int& v){
  if (e < REc){ u = e; v = e + Wc; }
  else { int k = e - REc; int i = k / (Wc-1); int j = k - i*(Wc-1); u = i*Wc + j; v = u + 1; }
}

__device__ __forceinline__ ull packw(float w, int e){
  return ((ull)__float_as_uint(w) << 32) | (unsigned)e;
}

// hook parent of round-(r-1) root x, as a pure function of frozen round-(r-1) state.
__device__ __forceinline__ int lazyparent(int x, const ull* __restrict__ bp,
                                          const int* __restrict__ Lold){
  ull p = bp[x];
  if (p == INF64) return x;
  int e = (int)(unsigned)p;
  int eu, ev; edge_uv(e, eu, ev);
  int lu = Lold[eu] & 0xFFFF;
  int other = (lu == x) ? (Lold[ev] & 0xFFFF) : lu;
  return (bp[other] == p && x < other) ? x : other;        // mutual pair: smaller id stays
}

// chase x (a round-(r-1) root) to its post-hook root, with tagged memo acceleration.
__device__ __forceinline__ int resolve(int x, int rtag, const int* __restrict__ Lnew,
                                       const ull* __restrict__ bp, const int* __restrict__ Lold){
  int mv = Lnew[x];
  if ((mv >> 24) == rtag) return mv & 0xFFFF;              // memo hit (benign race: exact value)
  while (true){
    int p = lazyparent(x, bp, Lold);
    if (p == x) return x;
    x = p;
    int mv2 = Lnew[x];
    if ((mv2 >> 24) == rtag) return mv2 & 0xFFFF;
  }
}

// fused: init + all 4 edge sums per pixel + round-0 per-vertex minima (no atomics)
__global__ void __launch_bounds__(256)
k_weights(const float* __restrict__ g, float* __restrict__ wf,
          int* __restrict__ L0, ull* __restrict__ b0, ull* __restrict__ b1, ull* __restrict__ b2,
          unsigned char* __restrict__ sel, int* __restrict__ act, int* __restrict__ outp){
  int t = blockIdx.x*256 + threadIdx.x;                    // [0, B*V)
  int b = t >> 16; int v = t & VM1;
  int i = v >> 8, j = v & (Wc-1);
  const bool hU = i > 0, hD = i < Hc-1, hL = j > 0, hR = j < Wc-1;
  const int oU = hU ? -Wc : 0, oD = hD ? Wc : 0, oL = hL ? -1 : 0, oR = hR ? 1 : 0;
  const float* p = g + (size_t)b*Cc*Vc + v;
  float sU = 0.f, sD = 0.f, sL = 0.f, sR = 0.f;
  #pragma unroll 4
  for (int c = 0; c < Cc; ++c){                            // sequential c order (bit-exact)
    const float* pc = p + (size_t)c*Vc;
    float x = pc[0];
    float dU = x - pc[oU];  float dD = x - pc[oD];         // (a-b)^2 == (b-a)^2 bitwise
    float dL = x - pc[oL];  float dR = x - pc[oR];
    sU += dU*dU; sD += dD*dD; sL += dL*dL; sR += dR*dR;
  }
  float wU = sU + 1.0f, wD = sD + 1.0f, wL = sL + 1.0f, wR = sR + 1.0f;
  int eU = v - Wc, eD = v, eL = REc + i*(Wc-1) + j - 1, eR = REc + i*(Wc-1) + j;
  ull m = INF64;
  if (hU){ ull x = packw(wU, eU); if (x < m) m = x; }
  if (hD){ ull x = packw(wD, eD); if (x < m) m = x; }
  if (hL){ ull x = packw(wL, eL); if (x < m) m = x; }
  if (hR){ ull x = packw(wR, eR); if (x < m) m = x; }
  b0[t] = m;                                               // round-0 minima (singleton comps)
  b1[t] = INF64; b2[t] = INF64;
  L0[t] = v;                                               // identity labels, tag 0
  float* wfb = wf + (size_t)b*Ec;
  unsigned char* selb = sel + (size_t)b*Ec;
  if (hD){ wfb[eD] = wD; selb[eD] = 0; }                   // canonical owner writes
  if (hR){ wfb[eR] = wR; selb[eR] = 0; }
  if (t < Bc*VM1){ outp[2*t] = 0; outp[2*t+1] = Wc; }      // ref fill value (edge 0)
  if (t < NRA*Bc) act[t] = 0;
}

// one Boruvka round: lazy hook(r-1) + relabel + scan(r), single dispatch.
__global__ void __launch_bounds__(256)
k_round(const float* __restrict__ wf, const int* __restrict__ LoldA, int* __restrict__ LnewA,
        const ull* __restrict__ bpA, ull* __restrict__ bcA, ull* __restrict__ bnA,
        unsigned char* __restrict__ sel, int* __restrict__ act, int r){
  int t = blockIdx.x*256 + threadIdx.x;
  int b = t >> 16;
  if (r > 1 && !act[r*Bc + b]) return;
  int v = t & VM1;
  const int base = b << 16;
  const int*  Lold = LoldA + base;
  int*        Lnew = LnewA + base;
  const ull*  bp   = bpA + base;
  int i = v >> 8, j = v & (Wc-1);
  int l0 = Lold[v] & 0xFFFF;

  if (l0 == v){                                            // v was a round-(r-1) root
    ull p = bp[v];
    if (p != INF64) sel[(size_t)b*Ec + (int)(unsigned)p] = 1;   // hook(r-1) selection
  }
  int rt = resolve(l0, r, Lnew, bp, Lold);
  Lnew[v] = (r << 24) | rt;
  if (rt == v) bnA[base + v] = INF64;                      // reset next-round buffer at new roots

  int lU = (i > 0)    ? (Lold[v - Wc] & 0xFFFF) : l0;
  int lD = (i < Hc-1) ? (Lold[v + Wc] & 0xFFFF) : l0;
  int lL = (j > 0)    ? (Lold[v - 1 ] & 0xFFFF) : l0;
  int lR = (j < Wc-1) ? (Lold[v + 1 ] & 0xFFFF) : l0;
  if (lU == l0 && lD == l0 && lL == l0 && lR == l0) return; // settled interior: no scan

  int rU = (lU == l0) ? rt : resolve(lU, r, Lnew, bp, Lold);
  int rD = (lD == l0) ? rt : ((lD == lU) ? rU : resolve(lD, r, Lnew, bp, Lold));
  int rL = (lL == l0) ? rt : ((lL == lU) ? rU : (lL == lD) ? rD : resolve(lL, r, Lnew, bp, Lold));
  int rR = (lR == l0) ? rt : ((lR == lU) ? rU : (lR == lD) ? rD : (lR == lL) ? rL : resolve(lR, r, Lnew, bp, Lold));

  const float* wfb = wf + (size_t)b*Ec;
  ull m = INF64;
  if (rU != rt){ int e = v - Wc;                 ull x = packw(wfb[e], e); if (x < m) m = x; }
  if (rD != rt){ int e = v;                      ull x = packw(wfb[e], e); if (x < m) m = x; }
  if (rL != rt){ int e = REc + i*(Wc-1) + j - 1; ull x = packw(wfb[e], e); if (x < m) m = x; }
  if (rR != rt){ int e = REc + i*(Wc-1) + j;     ull x = packw(wfb[e], e); if (x < m) m = x; }
  if (m != INF64){
    atomicMin(&bcA[base + rt], m);
    if (act[(r+1)*Bc + b] == 0) act[(r+1)*Bc + b] = 1;     // read-guarded, benign race
  }
}

// ---- ordered output compaction: count -> scatter (offsets recomputed in-scatter) ----
__global__ void __launch_bounds__(256)
k_cnt(const unsigned char* __restrict__ sel, int* __restrict__ blkcnt){
  int blk = blockIdx.x; int bb = blk >> 6; int kb = blk & (BPB-1);
  int base = kb*EPB;
  int off = threadIdx.x * 8;
  int c = 0;
  if (base + off < Ec){
    const unsigned int* p = (const unsigned int*)(sel + (size_t)bb*Ec + base + off);
    unsigned int s = p[0] + p[1];                          // per-byte sums <=2, no carry
    c = (s & 0xFF) + ((s>>8)&0xFF) + ((s>>16)&0xFF) + (s>>24);
  }
  int lane = threadIdx.x & 63, wave = threadIdx.x >> 6;
  #pragma unroll
  for (int o = 32; o; o >>= 1) c += __shfl_down(c, o, 64);
  __shared__ int sw[4];
  if (lane == 0) sw[wave] = c;
  __syncthreads();
  if (threadIdx.x == 0) blkcnt[blk] = sw[0] + sw[1] + sw[2] + sw[3];
}

__global__ void __launch_bounds__(256)
k_scatter(const unsigned char* __restrict__ sel, const int* __restrict__ blkcnt,
          int* __restrict__ outp){
  int blk = blockIdx.x; int bb = blk >> 6; int kb = blk & (BPB-1);
  __shared__ int s_boff;
  if (threadIdx.x < 64){                                   // wave 0: prefix of batch counts
    int c = ((int)threadIdx.x < kb) ? blkcnt[bb*BPB + threadIdx.x] : 0;
    #pragma unroll
    for (int o = 32; o; o >>= 1) c += __shfl_down(c, o, 64);
    if (threadIdx.x == 0) s_boff = c;
  }
  int base = kb*EPB;
  int off = threadIdx.x * 8;
  unsigned int a = 0, d = 0; int c = 0;
  if (base + off < Ec){
    const unsigned int* p = (const unsigned int*)(sel + (size_t)bb*Ec + base + off);
    a = p[0]; d = p[1];
    unsigned int s = a + d;
    c = (s & 0xFF) + ((s>>8)&0xFF) + ((s>>16)&0xFF) + (s>>24);
  }
  int lane = threadIdx.x & 63, wave = threadIdx.x >> 6;
  int x = c;
  #pragma unroll
  for (int o = 1; o < 64; o <<= 1){ int y = __shfl_up(x, o, 64); if (lane >= o) x += y; }
  __shared__ int sw[4];
  if (lane == 63) sw[wave] = x;
  __syncthreads();
  int woff = 0;
  #pragma unroll
  for (int w = 0; w < 4; ++w) if (w < wave) woff += sw[w];
  int pos = s_boff + woff + x - c;
  if (base + off < Ec){
    int* ob = outp + (size_t)bb*VM1*2;
    int ebase = base + off;
    #pragma unroll
    for (int k = 0; k < 8; ++k){
      unsigned int byte = ((k < 4) ? (a >> (8*k)) : (d >> (8*(k-4)))) & 0xFF;
      if (byte){ int e = ebase + k; int u, v; edge_uv(e, u, v); ob[2*pos] = u; ob[2*pos+1] = v; ++pos; }
    }
  }
}

extern "C" void kernel_launch(void* const* d_in, const int* in_sizes, int n_in,
                              void* d_out, int out_size, void* d_ws, size_t ws_size,
                              hipStream_t stream) {
  const float* g = (const float*)d_in[0];
  int* outp = (int*)d_out;

  char* ws = (char*)d_ws;
  size_t off = 0;
  auto alloc = [&](size_t bytes) -> void* {
    void* p = ws + off; off += (bytes + 511) & ~(size_t)511; return p;
  };
  ull* B[3];
  B[0] = (ull*)alloc((size_t)Bc*Vc*8);
  B[1] = (ull*)alloc((size_t)Bc*Vc*8);
  B[2] = (ull*)alloc((size_t)Bc*Vc*8);
  float* wf = (float*)alloc((size_t)Bc*Ec*4);
  int* LA0 = (int*)alloc((size_t)Bc*Vc*4);
  int* LA1 = (int*)alloc((size_t)Bc*Vc*4);
  unsigned char* sel = (unsigned char*)alloc((size_t)Bc*Ec);
  int* act  = (int*)alloc((size_t)NRA*Bc*4);
  int* blkcnt = (int*)alloc((size_t)Bc*BPB*4);

  const int gv = (Bc*Vc)/256;                              // 2048 blocks

  k_weights<<<gv, 256, 0, stream>>>(g, wf, LA0, B[0], B[1], B[2], sel, act, outp);
  for (int r = 1; r <= NKR; ++r){
    const int* Lold = (r & 1) ? LA0 : LA1;
    int*       Lnew = (r & 1) ? LA1 : LA0;
    k_round<<<gv, 256, 0, stream>>>(wf, Lold, Lnew,
                                    B[(r-1)%3], B[r%3], B[(r+1)%3],
                                    sel, act, r);
  }
  k_cnt    <<<Bc*BPB, 256, 0, stream>>>(sel, blkcnt);
  k_scatter<<<Bc*BPB, 256, 0, stream>>>(sel, blkcnt, outp);
}

// Round 7
// 248.302 us; speedup vs baseline: 1.3751x; 1.3751x over previous
//
#include <hip/hip_runtime.h>
#include <stdint.h>

typedef unsigned long long ull;

#define Bc 8
#define Cc 64
#define Hc 256
#define Wc 256
#define Vc (Hc*Wc)            // 65536
#define REc ((Hc-1)*Wc)       // 65280 row (down) edges
#define Ec (REc + Hc*(Wc-1))  // 130560 total edges
#define VM1 (Vc-1)            // 65535
#define INF64 0xFFFFFFFFFFFFFFFFull
#define NRND 16               // 16 hooks: components halve per hook, 2^16 = V
#define EPB 8192              // edges per block in compaction (1024 thr x 8 B)
#define BPB 16                // blocks per batch = ceil(Ec/EPB)

__device__ __forceinline__ void edge_uv(int e, int& u, int& v){
  if (e < REc){ u = e; v = e + Wc; }
  else { int k = e - REc; int i = k / (Wc-1); int j = k - i*(Wc-1); u = i*Wc + j; v = u + 1; }
}

__device__ __forceinline__ ull packw(float w, int e){
  return ((ull)__float_as_uint(w) << 32) | (unsigned)e;
}

__device__ __forceinline__ int chase(const int* __restrict__ parB, int x){
  int p = parB[x];
  while (p != x){ x = p; p = parB[x]; }
  return x;
}

// fused: init + all 4 edge sums per pixel + round-0 per-vertex minima (no atomics)
__global__ void __launch_bounds__(1024)
k_weights(const float* __restrict__ g, float* __restrict__ wf,
          int* __restrict__ L, int* __restrict__ par,
          ull* __restrict__ b0, ull* __restrict__ b1,
          unsigned char* __restrict__ sel, int* __restrict__ act, int* __restrict__ outp){
  int t = blockIdx.x*1024 + threadIdx.x;                   // [0, B*V)
  int b = t >> 16; int v = t & VM1;
  int i = v >> 8, j = v & (Wc-1);
  const bool hU = i > 0, hD = i < Hc-1, hL = j > 0, hR = j < Wc-1;
  const int oU = hU ? -Wc : 0, oD = hD ? Wc : 0, oL = hL ? -1 : 0, oR = hR ? 1 : 0;
  const float* p = g + (size_t)b*Cc*Vc + v;
  float sU = 0.f, sD = 0.f, sL = 0.f, sR = 0.f;
  #pragma unroll 4
  for (int c = 0; c < Cc; ++c){                            // sequential c order (bit-exact)
    const float* pc = p + (size_t)c*Vc;
    float x = pc[0];
    float dU = x - pc[oU];  float dD = x - pc[oD];         // (a-b)^2 == (b-a)^2 bitwise
    float dL = x - pc[oL];  float dR = x - pc[oR];
    sU += dU*dU; sD += dD*dD; sL += dL*dL; sR += dR*dR;
  }
  float wU = sU + 1.0f, wD = sD + 1.0f, wL = sL + 1.0f, wR = sR + 1.0f;
  int eU = v - Wc, eD = v, eL = REc + i*(Wc-1) + j - 1, eR = REc + i*(Wc-1) + j;
  ull m = INF64;
  if (hU){ ull x = packw(wU, eU); if (x < m) m = x; }
  if (hD){ ull x = packw(wD, eD); if (x < m) m = x; }
  if (hL){ ull x = packw(wL, eL); if (x < m) m = x; }
  if (hR){ ull x = packw(wR, eR); if (x < m) m = x; }
  b0[t] = m;                                               // round-0 minima (singleton comps)
  b1[t] = INF64;
  L[t] = v; par[t] = v;
  float* wfb = wf + (size_t)b*Ec;
  unsigned char* selb = sel + (size_t)b*Ec;
  if (hD){ wfb[eD] = wD; selb[eD] = 0; }                   // canonical owner writes
  if (hR){ wfb[eR] = wR; selb[eR] = 0; }
  if (t < Bc*VM1){ outp[2*t] = 0; outp[2*t+1] = Wc; }      // ref fill value (edge 0)
  if (t < (NRND+2)*Bc) act[t] = 0;
}

// rounds >=1: fused {relabel to hook-forest root} + {vertex-centric scan}, root-only
// reset of next buffer, with settled-interior fast path.  (R4-proven logic)
__global__ void __launch_bounds__(1024)
k_scanmerge(const float* __restrict__ wf, int* __restrict__ L,
            const int* __restrict__ par,
            ull* __restrict__ bcur, ull* __restrict__ bnxt,
            const int* __restrict__ act, int r){
  int t = blockIdx.x*1024 + threadIdx.x;
  int b = t >> 16;
  if (!act[r*Bc + b]) return;
  int v = t & VM1; const int base = b << 16;
  const int* parB = par + base;
  int Lt0 = L[t];
  int i = v >> 8, j = v & (Wc-1);
  int Lu = (i > 0)    ? L[base + v - Wc] : Lt0;
  int Ld = (i < Hc-1) ? L[base + v + Wc] : Lt0;
  int Ll = (j > 0)    ? L[base + v - 1 ] : Lt0;
  int Lr = (j < Wc-1) ? L[base + v + 1 ] : Lt0;
  if ((Lu==Lt0) & (Ld==Lt0) & (Ll==Lt0) & (Lr==Lt0)){      // settled neighborhood
    if (Lt0 != v) return;                                  // interior non-root: done
    if (parB[v] == v){ bnxt[t] = INF64; return; }          // true root: reset next buf
    /* dead root (stale self-label): fall through to refresh L */
  }
  int rt = chase(parB, Lt0);
  if (rt != Lt0) L[t] = rt;                                // racy-read-benign: readers re-chase
  if (v == rt) bnxt[t] = INF64;                            // root-only reset for round r+1
  const float* wfb = wf + (size_t)b*Ec;
  ull m = INF64;
  if (Lu != Lt0 && Lu != rt && chase(parB, Lu) != rt){
    int e = v - Wc; ull x = packw(wfb[e], e); if (x < m) m = x; }
  if (Ld != Lt0 && Ld != rt && chase(parB, Ld) != rt){
    int e = v;      ull x = packw(wfb[e], e); if (x < m) m = x; }
  if (Ll != Lt0 && Ll != rt && chase(parB, Ll) != rt){
    int e = REc + i*(Wc-1) + j - 1; ull x = packw(wfb[e], e); if (x < m) m = x; }
  if (Lr != Lt0 && Lr != rt && chase(parB, Lr) != rt){
    int e = REc + i*(Wc-1) + j;     ull x = packw(wfb[e], e); if (x < m) m = x; }
  if (m != INF64) atomicMin(&bcur[base + rt], m);
}

// roots pick best edge, mutual-pair break (smaller id stays root), write par + sel
__global__ void __launch_bounds__(1024)
k_hook(const int* __restrict__ L, const ull* __restrict__ bcur,
       int* __restrict__ par, unsigned char* __restrict__ sel, int* __restrict__ act, int r){
  int t = blockIdx.x*1024 + threadIdx.x;
  int b = t >> 16;
  if (r > 0 && !act[r*Bc + b]) return;
  int v = t & VM1;
  if (L[t] != v) return;                                   // roots only (L fresh for roots)
  const int base = b << 16;
  ull p = bcur[t];
  int pr = v;
  if (p != INF64){
    int e = (int)(unsigned)p; int eu, ev; edge_uv(e, eu, ev);
    int cu = L[base + eu], cv = L[base + ev];
    int other = (cu == v) ? cv : cu;
    sel[(size_t)b*Ec + e] = 1;
    if (act[(r+1)*Bc + b] == 0) act[(r+1)*Bc + b] = 1;     // read-guarded, benign race
    pr = (bcur[base + other] == p && v < other) ? v : other;
  }
  par[t] = pr;
}

// ---- ordered output compaction: count -> scatter (offsets recomputed in-scatter) ----
__global__ void __launch_bounds__(1024)
k_cnt(const unsigned char* __restrict__ sel, int* __restrict__ blkcnt){
  int blk = blockIdx.x; int bb = blk / BPB; int kb = blk % BPB;
  int base = kb*EPB;
  int off = threadIdx.x * 8;
  int c = 0;
  if (base + off < Ec){
    const unsigned int* p = (const unsigned int*)(sel + (size_t)bb*Ec + base + off);
    unsigned int s = p[0] + p[1];                          // per-byte sums <=2, no carry
    c = (s & 0xFF) + ((s>>8)&0xFF) + ((s>>16)&0xFF) + (s>>24);
  }
  int lane = threadIdx.x & 63, wave = threadIdx.x >> 6;
  #pragma unroll
  for (int o = 32; o; o >>= 1) c += __shfl_down(c, o, 64);
  __shared__ int sw[16];
  if (lane == 0) sw[wave] = c;
  __syncthreads();
  if (threadIdx.x == 0){
    int s = 0;
    #pragma unroll
    for (int w = 0; w < 16; ++w) s += sw[w];
    blkcnt[blk] = s;
  }
}

__global__ void __launch_bounds__(1024)
k_scatter(const unsigned char* __restrict__ sel, const int* __restrict__ blkcnt,
          int* __restrict__ outp){
  int blk = blockIdx.x; int bb = blk / BPB; int kb = blk % BPB;
  __shared__ int s_boff;
  if (threadIdx.x < 64){                                   // wave 0: prefix of batch counts
    int c = ((int)threadIdx.x < kb) ? blkcnt[bb*BPB + threadIdx.x] : 0;
    #pragma unroll
    for (int o = 32; o; o >>= 1) c += __shfl_down(c, o, 64);
    if (threadIdx.x == 0) s_boff = c;
  }
  int base = kb*EPB;
  int off = threadIdx.x * 8;
  unsigned int a = 0, d = 0; int c = 0;
  if (base + off < Ec){
    const unsigned int* p = (const unsigned int*)(sel + (size_t)bb*Ec + base + off);
    a = p[0]; d = p[1];
    unsigned int s = a + d;
    c = (s & 0xFF) + ((s>>8)&0xFF) + ((s>>16)&0xFF) + (s>>24);
  }
  int lane = threadIdx.x & 63, wave = threadIdx.x >> 6;
  int x = c;
  #pragma unroll
  for (int o = 1; o < 64; o <<= 1){ int y = __shfl_up(x, o, 64); if (lane >= o) x += y; }
  __shared__ int sw[16];
  if (lane == 63) sw[wave] = x;
  __syncthreads();
  int woff = 0;
  #pragma unroll
  for (int w = 0; w < 16; ++w) if (w < wave) woff += sw[w];
  int pos = s_boff + woff + x - c;
  if (base + off < Ec){
    int* ob = outp + (size_t)bb*VM1*2;
    int ebase = base + off;
    #pragma unroll
    for (int k = 0; k < 8; ++k){
      unsigned int byte = ((k < 4) ? (a >> (8*k)) : (d >> (8*(k-4)))) & 0xFF;
      if (byte){ int e = ebase + k; int u, v; edge_uv(e, u, v); ob[2*pos] = u; ob[2*pos+1] = v; ++pos; }
    }
  }
}

extern "C" void kernel_launch(void* const* d_in, const int* in_sizes, int n_in,
                              void* d_out, int out_size, void* d_ws, size_t ws_size,
                              hipStream_t stream) {
  const float* g = (const float*)d_in[0];
  int* outp = (int*)d_out;

  char* ws = (char*)d_ws;
  size_t off = 0;
  auto alloc = [&](size_t bytes) -> void* {
    void* p = ws + off; off += (bytes + 511) & ~(size_t)511; return p;
  };
  ull* b0 = (ull*)alloc((size_t)Bc*Vc*8);
  ull* b1 = (ull*)alloc((size_t)Bc*Vc*8);
  float* wf = (float*)alloc((size_t)Bc*Ec*4);
  int* L   = (int*)alloc((size_t)Bc*Vc*4);
  int* par = (int*)alloc((size_t)Bc*Vc*4);
  unsigned char* sel = (unsigned char*)alloc((size_t)Bc*Ec);
  int* act  = (int*)alloc((size_t)(NRND+2)*Bc*4);
  int* blkcnt = (int*)alloc((size_t)Bc*BPB*4);

  const int gv = (Bc*Vc)/1024;                             // 512 WGs, 1024-thr

  k_weights<<<gv, 1024, 0, stream>>>(g, wf, L, par, b0, b1, sel, act, outp);
  k_hook   <<<gv, 1024, 0, stream>>>(L, b0, par, sel, act, 0);
  for (int r = 1; r < NRND; ++r){
    ull* bcur = (r & 1) ? b1 : b0;
    ull* bnxt = (r & 1) ? b0 : b1;
    k_scanmerge<<<gv, 1024, 0, stream>>>(wf, L, par, bcur, bnxt, act, r);
    k_hook     <<<gv, 1024, 0, stream>>>(L, bcur, par, sel, act, r);
  }
  k_cnt    <<<Bc*BPB, 1024, 0, stream>>>(sel, blkcnt);
  k_scatter<<<Bc*BPB, 1024, 0, stream>>>(sel, blkcnt, outp);
}